// Round 8
// baseline (83.209 us; speedup 1.0000x reference)
//
#include <hip/hip_runtime.h>
#include <math.h>

// Problem constants (match reference)
constexpr int   B_    = 2048;
constexpr int   L_    = 8192;
constexpr int   G_    = 256;
constexpr float BETA_ = 0.01f;
constexpr float BIG_  = 1024.0f;   // linear y-flag encoding (validated R0-R7)

constexpr int   SENTW  = 8192;     // sentinel word in s_enc (pads gather to 0)
constexpr int   ENCW   = 8256;     // LDS words (33 KB)
constexpr int   PCAP   = 12032;    // perm capacity: 8192 + 256*15 (pad-to-16 worst case)
constexpr int   SEGCAP = 768;      // max segments: 8192/16 + 256

// log(sigmoid(-x)) = -softplus(x) = -(max(x,0) + log(1 + exp(-|x|)))
__device__ __forceinline__ float log_sigmoid_neg(float x) {
    return -(fmaxf(x, 0.0f) + __logf(1.0f + __expf(-fabsf(x))));
}

// Swizzled storage word for label l: phase-1 thread t writes labels [8t,8t+8)
// as two b128s at float4-slots {t, 1024+t} (16B-consecutive across lanes ->
// conflict-free). Bijective on [0,8192); baked into perm by the prep kernel.
__device__ __forceinline__ int swzF(int l) {
    return (((l >> 2) & 1) << 12) + ((l >> 3) << 2) + (l & 3);
}

// ---------------------------------------------------------------------------
// Prep (1 block x 1024): counting sort -> swizzled perm, padded per group to
// a multiple of 16 (pad entries -> SENTW, which gathers 0). seg_gid[s] = group
// of segment s; hdr[0] = total segments (<= 768 for any distribution).
// ---------------------------------------------------------------------------
extern "C" __global__ __launch_bounds__(1024)
void prep_kernel(const int* __restrict__ group_ids,
                 unsigned short* __restrict__ perm,
                 unsigned char*  __restrict__ seg_gid,
                 int*            __restrict__ hdr)
{
    __shared__ int s_cnt[G_];
    __shared__ int s_scan[G_];
    __shared__ int s_cur[G_];

    const int t = threadIdx.x;
    if (t < G_) s_cnt[t] = 0;

    const int4 a = ((const int4*)group_ids)[2 * t];
    const int4 bq = ((const int4*)group_ids)[2 * t + 1];
    __syncthreads();

    atomicAdd(&s_cnt[a.x], 1);  atomicAdd(&s_cnt[a.y], 1);
    atomicAdd(&s_cnt[a.z], 1);  atomicAdd(&s_cnt[a.w], 1);
    atomicAdd(&s_cnt[bq.x], 1); atomicAdd(&s_cnt[bq.y], 1);
    atomicAdd(&s_cnt[bq.z], 1); atomicAdd(&s_cnt[bq.w], 1);
    __syncthreads();

    int n = 0, pc = 0;
    if (t < G_) { n = s_cnt[t]; pc = (n + 15) & ~15; s_scan[t] = pc; }
    __syncthreads();
    for (int off = 1; off < G_; off <<= 1) {
        int v = 0;
        if (t < G_ && t >= off) v = s_scan[t - off];
        __syncthreads();
        if (t < G_) s_scan[t] += v;
        __syncthreads();
    }

    if (t < G_) {
        const int gbase = s_scan[t] - pc;
        s_cur[t] = gbase;
        const int segb = gbase >> 4;
        for (int i = 0; i < (pc >> 4); ++i) seg_gid[segb + i] = (unsigned char)t;
        for (int i = n; i < pc; ++i)        perm[gbase + i] = (unsigned short)SENTW;
    }
    if (t == 0) hdr[0] = s_scan[G_ - 1] >> 4;
    __syncthreads();

    const int l = 8 * t;
    perm[atomicAdd(&s_cur[a.x], 1)]  = (unsigned short)swzF(l + 0);
    perm[atomicAdd(&s_cur[a.y], 1)]  = (unsigned short)swzF(l + 1);
    perm[atomicAdd(&s_cur[a.z], 1)]  = (unsigned short)swzF(l + 2);
    perm[atomicAdd(&s_cur[a.w], 1)]  = (unsigned short)swzF(l + 3);
    perm[atomicAdd(&s_cur[bq.x], 1)] = (unsigned short)swzF(l + 4);
    perm[atomicAdd(&s_cur[bq.y], 1)] = (unsigned short)swzF(l + 5);
    perm[atomicAdd(&s_cur[bq.z], 1)] = (unsigned short)swzF(l + 6);
    perm[atomicAdd(&s_cur[bq.w], 1)] = (unsigned short)swzF(l + 7);
}

// ---------------------------------------------------------------------------
// PROBE: pure float4 streaming read of 32 MB (m13 pattern). Its rocprof dur
// measures the max delivered read rate for these buffers in this harness
// state. dur ~8us => >=4 TB/s achievable (kernels are structurally bound);
// dur ~18us => ~1.8 TB/s ceiling (R0/R2 were already at roofline).
// ---------------------------------------------------------------------------
extern "C" __global__ __launch_bounds__(256)
void probe_kernel(const float* __restrict__ src)
{
    const float4* p = (const float4*)src;
    const size_t  i = (size_t)blockIdx.x * 256 + threadIdx.x;   // 524288 threads
    float4 s = make_float4(0.f, 0.f, 0.f, 0.f);
    #pragma unroll
    for (int k = 0; k < 4; ++k) {
        const float4 v = p[i + (size_t)k * 524288];             // 2M float4 = 32 MB
        s.x += v.x; s.y += v.y; s.z += v.z; s.w += v.w;
    }
    asm volatile("" :: "v"(s.x), "v"(s.y), "v"(s.z), "v"(s.w));
}

// ---------------------------------------------------------------------------
// Main: one 1024-thread block (16 waves) per row; 2 blocks/CU (66 KB LDS),
// 32 waves/CU.
//  Phase 1: thread t loads labels [8t,8t+8) (x float4 x2, y int4 x2,
//    coalesced), encodes logsig + BIG*y, writes TWO conflict-free b128s into
//    the swizzled linear LDS image. No scatter, no zero-init, no rank reads.
//  Phase 2 (after ONE barrier): lane s (< nseg <= 768) owns one 16-label
//    group-segment: 4x ushort4 perm reads (24 KB table, L1-resident across
//    all 2048 blocks) + 16 LDS gathers + 15 adds -> one atomicAdd to
//    partial[b][g] (1-4 adders per address).
// ---------------------------------------------------------------------------
extern "C" __global__ __launch_bounds__(1024, 8)
void meta_gather_kernel(const float* __restrict__ logits,
                        const int*   __restrict__ true_y,
                        const unsigned short* __restrict__ perm,
                        const unsigned char*  __restrict__ seg_gid,
                        const int*   __restrict__ hdr,
                        float*       __restrict__ partial)   // [B][G]
{
    __shared__ float s_enc[ENCW];        // 33 KB swizzled encoded row

    const int t = threadIdx.x;           // 0..1023
    const int b = blockIdx.x;

    if (t == 0) s_enc[SENTW] = 0.0f;

    const float4* lg4 = (const float4*)(logits + (size_t)b * L_);
    const int4*   ty4 = (const int4*)(true_y + (size_t)b * L_);

    const float4 x0 = lg4[2 * t];
    const float4 x1 = lg4[2 * t + 1];
    const int4   y0 = ty4[2 * t];
    const int4   y1 = ty4[2 * t + 1];

    float4 E0, E1;
    E0.x = log_sigmoid_neg(x0.x) + (y0.x ? BIG_ : 0.0f);
    E0.y = log_sigmoid_neg(x0.y) + (y0.y ? BIG_ : 0.0f);
    E0.z = log_sigmoid_neg(x0.z) + (y0.z ? BIG_ : 0.0f);
    E0.w = log_sigmoid_neg(x0.w) + (y0.w ? BIG_ : 0.0f);
    E1.x = log_sigmoid_neg(x1.x) + (y1.x ? BIG_ : 0.0f);
    E1.y = log_sigmoid_neg(x1.y) + (y1.y ? BIG_ : 0.0f);
    E1.z = log_sigmoid_neg(x1.z) + (y1.z ? BIG_ : 0.0f);
    E1.w = log_sigmoid_neg(x1.w) + (y1.w ? BIG_ : 0.0f);

    ((float4*)s_enc)[t]        = E0;     // labels 8t..8t+3  (swzF layout)
    ((float4*)s_enc)[1024 + t] = E1;     // labels 8t+4..8t+7
    __syncthreads();

    const int nseg = hdr[0];
    if (t < nseg) {
        const int g = seg_gid[t];
        const ushort4* pp = (const ushort4*)(perm + 16 * t);
        float s = 0.0f;
        #pragma unroll
        for (int k = 0; k < 4; ++k) {
            const ushort4 q = pp[k];
            s += s_enc[q.x] + s_enc[q.y] + s_enc[q.z] + s_enc[q.w];
        }
        atomicAdd(&partial[(size_t)b * G_ + g], s);
    }
}

// ---------------------------------------------------------------------------
// Finalize: decode BIG encoding, BCE terms, global reduce. 2 MB read, tiny.
// ---------------------------------------------------------------------------
extern "C" __global__ __launch_bounds__(1024)
void finalize_kernel(const float* __restrict__ partial,
                     float* __restrict__ out)
{
    __shared__ float s_part[16];

    const int t   = threadIdx.x;
    const int idx = blockIdx.x * 1024 + t;    // 512 blocks x 1024 = 524288

    const float enc = partial[idx];
    const int   k   = __float2int_rn(enc * (1.0f / BIG_));   // # true labels (exact)
    const float gl  = enc - BIG_ * (float)k;                 // sum log(1-sig)

    float term;
    if (k != 0) {
        term = fmaxf(gl, -100.0f);                    // meta_y = 1: log(p)
    } else {
        // empty/all-false group: gl<=0; gl==0 -> log1p(-1) = -inf -> clamp
        term = fmaxf(log1pf(-__expf(gl)), -100.0f);   // meta_y = 0
    }

    #pragma unroll
    for (int off = 32; off > 0; off >>= 1)
        term += __shfl_down(term, off, 64);
    if ((t & 63) == 0) s_part[t >> 6] = term;
    __syncthreads();

    if (t == 0) {
        float s = 0.0f;
        #pragma unroll
        for (int wv = 0; wv < 16; ++wv) s += s_part[wv];
        atomicAdd(out, s * (-BETA_ / ((float)B_ * (float)G_)));
    }
}

extern "C" void kernel_launch(void* const* d_in, const int* in_sizes, int n_in,
                              void* d_out, int out_size, void* d_ws, size_t ws_size,
                              hipStream_t stream) {
    const float* logits    = (const float*)d_in[0];
    const int*   true_y    = (const int*)d_in[1];
    const int*   group_ids = (const int*)d_in[2];
    float*       out       = (float*)d_out;

    // workspace: [0,2MB) partial f32; [2MB,+24KB) perm u16; then seg_gid, hdr
    float*          partial = (float*)d_ws;
    unsigned short* perm    = (unsigned short*)((char*)d_ws + 2097152);
    unsigned char*  seg_gid = (unsigned char*)((char*)d_ws + 2097152 + 24576);
    int*            hdr     = (int*)((char*)d_ws + 2097152 + 24576 + 1024);

    hipMemsetAsync(partial, 0, (size_t)B_ * G_ * 4, stream);
    hipMemsetAsync(out, 0, sizeof(float), stream);

    prep_kernel<<<1, 1024, 0, stream>>>(group_ids, perm, seg_gid, hdr);
    // BW probe: second 32 MB of logits (outside L2, same L3 state as main's
    // inputs). Decisive ceiling measurement + L3 prefetch for rows 1024-2047.
    probe_kernel<<<2048, 256, 0, stream>>>(logits + (size_t)1024 * L_);
    meta_gather_kernel<<<B_, 1024, 0, stream>>>(logits, true_y, perm, seg_gid, hdr, partial);
    finalize_kernel<<<(B_ * G_) / 1024, 1024, 0, stream>>>(partial, out);
}

// Round 9
// 45.797 us; speedup vs baseline: 1.8169x; 1.8169x over previous
//
#include <hip/hip_runtime.h>
#include <math.h>

// Problem constants (match reference)
constexpr int   B_    = 2048;
constexpr int   L_    = 8192;
constexpr int   G_    = 256;
constexpr float BETA_ = 0.01f;
constexpr float BIG_  = 1024.0f;   // y-flag encoding (validated absmax 0.0 in prior rounds)

constexpr int   HALF  = L_ / 2;                 // 4096 labels per half-row
constexpr int   PMAX  = HALF + G_ * 3;          // padded rank space per half = 4864 floats (19456 B)

// log(sigmoid(-x)) = -softplus(x) = -(max(x,0) + log(1 + exp(-|x|)))
__device__ __forceinline__ float log_sigmoid_neg(float x) {
    return -(fmaxf(x, 0.0f) + __logf(1.0f + __expf(-fabsf(x))));
}

// ---------------------------------------------------------------------------
// Prep: counting sort into PADDED rank space, one block per HALF-row slab.
// Each (half, group) extent padded to a multiple of 4 floats so the main
// kernel can use aligned ds_read_b128. offs[h][g+1]-offs[h][g] = ceil(n/4)*4.
// Total per half <= 4096 + 3*256 = 4864 (u16-safe).
// ---------------------------------------------------------------------------
extern "C" __global__ __launch_bounds__(1024)
void build_rank_kernel(const int* __restrict__ group_ids,
                       int* __restrict__ g_offs,          // [2][257]
                       unsigned short* __restrict__ g_rank) // [8192], rank within half
{
    __shared__ int s_cnt[G_];
    __shared__ int s_scan[G_];
    __shared__ int s_cur[G_];

    const int t = threadIdx.x;          // 0..1023
    const int h = blockIdx.x;           // 0..1

    if (t < G_) s_cnt[t] = 0;

    const int4 ids = ((const int4*)group_ids)[h * 1024 + t];   // 4 labels/thread
    __syncthreads();

    atomicAdd(&s_cnt[ids.x], 1);
    atomicAdd(&s_cnt[ids.y], 1);
    atomicAdd(&s_cnt[ids.z], 1);
    atomicAdd(&s_cnt[ids.w], 1);
    __syncthreads();

    if (t < G_) s_scan[t] = (s_cnt[t] + 3) & ~3;
    __syncthreads();
    for (int off = 1; off < G_; off <<= 1) {
        int v = 0;
        if (t < G_ && t >= off) v = s_scan[t - off];
        __syncthreads();
        if (t < G_) s_scan[t] += v;
        __syncthreads();
    }

    if (t < G_) {
        const int excl = s_scan[t] - ((s_cnt[t] + 3) & ~3);   // padded start
        s_cur[t] = excl;
        g_offs[h * 257 + t] = excl;
    }
    if (t == 0) g_offs[h * 257 + G_] = s_scan[G_ - 1];
    __syncthreads();

    const int l = h * HALF + t * 4;
    g_rank[l + 0] = (unsigned short)atomicAdd(&s_cur[ids.x], 1);
    g_rank[l + 1] = (unsigned short)atomicAdd(&s_cur[ids.y], 1);
    g_rank[l + 2] = (unsigned short)atomicAdd(&s_cur[ids.z], 1);
    g_rank[l + 3] = (unsigned short)atomicAdd(&s_cur[ids.w], 1);
}

// ---------------------------------------------------------------------------
// Main: one 256-thread block (4 waves) per HALF-row.
//  - LDS 19.5 KB -> 8 blocks/CU -> 32 waves/CU (100% occupancy).
//  - Phase 1: coalesced float4/int4 loads, encode, scatter b32 into padded
//    rank space. Phase 2: ALL 256 threads, aligned ds_read_b128 contiguous
//    per-group extents (avg 4 iters). One global atomicAdd per (b,g) half —
//    exactly 2 adders per address -> deterministic f32 sum.
// ---------------------------------------------------------------------------
extern "C" __global__ __launch_bounds__(256, 8)
void meta_loss_kernel(const float* __restrict__ logits,
                      const int*   __restrict__ true_y,
                      const int*   __restrict__ g_offs,
                      const unsigned short* __restrict__ g_rank,
                      float*       __restrict__ partial)   // [B][G]
{
    __shared__ float s_row[PMAX];            // 19456 B

    const int t = threadIdx.x;               // 0..255
    const int b = blockIdx.x >> 1;
    const int h = blockIdx.x & 1;

    const float4*  lg = (const float4*)(logits + (size_t)b * L_ + h * HALF);
    const int4*    ty = (const int4*)(true_y + (size_t)b * L_ + h * HALF);
    const ushort4* rk = (const ushort4*)(g_rank + h * HALF);
    float4* s_row4 = (float4*)s_row;

    // group extent for this half (L2-hot)
    const int o0 = g_offs[h * 257 + t];
    const int o1 = g_offs[h * 257 + t + 1];

    // zero-init padded rank space: 1216 float4 over 256 threads
    #pragma unroll
    for (int i = 0; i < 5; ++i) {
        const int j = i * 256 + t;
        if (j < PMAX / 4) s_row4[j] = make_float4(0.f, 0.f, 0.f, 0.f);
    }
    __syncthreads();

    // ---- Phase 1: stream slab -> padded-permuted encoded LDS ----
    #pragma unroll
    for (int i = 0; i < HALF / (4 * 256); ++i) {          // 4 iters
        const int idx = i * 256 + t;
        const float4  x = lg[idx];
        const int4    y = ty[idx];
        const ushort4 r = rk[idx];
        s_row[r.x] = log_sigmoid_neg(x.x) + (y.x ? BIG_ : 0.0f);
        s_row[r.y] = log_sigmoid_neg(x.y) + (y.y ? BIG_ : 0.0f);
        s_row[r.z] = log_sigmoid_neg(x.z) + (y.z ? BIG_ : 0.0f);
        s_row[r.w] = log_sigmoid_neg(x.w) + (y.w ? BIG_ : 0.0f);
    }
    __syncthreads();

    // ---- Phase 2: vectorized contiguous per-group sum (all 256 threads) ----
    float4 a4 = make_float4(0.f, 0.f, 0.f, 0.f);
    for (int j = o0; j < o1; j += 4) {
        const float4 v = *(const float4*)&s_row[j];
        a4.x += v.x; a4.y += v.y; a4.z += v.z; a4.w += v.w;
    }
    const float enc = (a4.x + a4.y) + (a4.z + a4.w);

    if (o1 > o0)                              // skip groups empty in this half
        atomicAdd(&partial[b * G_ + t], enc);
}

// ---------------------------------------------------------------------------
// Finalize: decode BIG encoding, BCE terms, global reduce. 2 MB read, tiny.
// ---------------------------------------------------------------------------
extern "C" __global__ __launch_bounds__(1024)
void finalize_kernel(const float* __restrict__ partial,
                     float* __restrict__ out)
{
    __shared__ float s_part[16];

    const int t   = threadIdx.x;
    const int idx = blockIdx.x * 1024 + t;    // 512 blocks x 1024 = 524288

    const float enc = partial[idx];
    const int   k   = __float2int_rn(enc * (1.0f / BIG_));   // # true labels
    const float gl  = enc - BIG_ * (float)k;                 // sum log(1-sig)

    float term;
    if (k != 0) {
        term = fmaxf(gl, -100.0f);                    // meta_y = 1: log(p)
    } else {
        // empty/all-false group: gl<=0; gl==0 -> log1p(-1) = -inf -> clamp
        term = fmaxf(log1pf(-__expf(gl)), -100.0f);   // meta_y = 0
    }

    #pragma unroll
    for (int off = 32; off > 0; off >>= 1)
        term += __shfl_down(term, off, 64);
    if ((t & 63) == 0) s_part[t >> 6] = term;
    __syncthreads();

    if (t == 0) {
        float s = 0.0f;
        #pragma unroll
        for (int w = 0; w < 16; ++w) s += s_part[w];
        atomicAdd(out, s * (-BETA_ / ((float)B_ * (float)G_)));
    }
}

extern "C" void kernel_launch(void* const* d_in, const int* in_sizes, int n_in,
                              void* d_out, int out_size, void* d_ws, size_t ws_size,
                              hipStream_t stream) {
    const float* logits    = (const float*)d_in[0];
    const int*   true_y    = (const int*)d_in[1];
    const int*   group_ids = (const int*)d_in[2];
    float*       out       = (float*)d_out;

    // workspace: [0,2MB) partial f32; [2MB,+16KB) rank u16; then offs
    float*          partial = (float*)d_ws;
    unsigned short* g_rank  = (unsigned short*)((char*)d_ws + (size_t)B_ * G_ * 4);
    int*            g_offs  = (int*)((char*)d_ws + (size_t)B_ * G_ * 4 + L_ * 2);

    hipMemsetAsync(partial, 0, (size_t)B_ * G_ * 4, stream);
    hipMemsetAsync(out, 0, sizeof(float), stream);

    build_rank_kernel<<<2, 1024, 0, stream>>>(group_ids, g_offs, g_rank);
    meta_loss_kernel<<<2 * B_, 256, 0, stream>>>(logits, true_y, g_offs, g_rank, partial);
    finalize_kernel<<<(B_ * G_) / 1024, 1024, 0, stream>>>(partial, out);
}